// Round 1
// baseline (892.363 us; speedup 1.0000x reference)
//
#include <hip/hip_runtime.h>

// ---------------------------------------------------------------------------
// Problem constants (fixed by the reference): B=2, T=1024, S=2048, D=4096,
// N=32 q-heads, KH=8 kv-heads, H=128. segment_ids are all-ones in the test
// (start=first=0); we still compute start[b] from segment_ids.
// ---------------------------------------------------------------------------
constexpr int Bc  = 2;
constexpr int Tc  = 1024;
constexpr int Dc  = 4096;
constexpr int NHc = 32;
constexpr int KHc = 8;
constexpr int Hc  = 128;

typedef __bf16 bf16;
typedef bf16  bf16x8  __attribute__((ext_vector_type(8)));
typedef float floatx4 __attribute__((ext_vector_type(4)));

#define MFMA16(a, b, c) __builtin_amdgcn_mfma_f32_16x16x32_bf16((a), (b), (c), 0, 0, 0)

// ---------------------------------------------------------------------------
// start[b] = index of first nonzero segment id (0 if none) — trivial scan.
// ---------------------------------------------------------------------------
__global__ void seg_scan(const int* __restrict__ seg, int* __restrict__ start) {
    int b = threadIdx.x;
    if (b >= Bc) return;
    int f = 0;
    for (int t = 0; t < Tc; ++t) {
        if (seg[b * Tc + t] != 0) { f = t; break; }
    }
    start[b] = f;
}

// ---------------------------------------------------------------------------
// Transpose + fp32->bf16 convert:  out[C x R] = in[R x C]^T. 32x32 LDS tile.
// ---------------------------------------------------------------------------
__global__ __launch_bounds__(256) void transpose_cvt(const float* __restrict__ in,
                                                     bf16* __restrict__ out,
                                                     int R, int C) {
    __shared__ float tile[32][33];
    const int c0 = blockIdx.x * 32, r0 = blockIdx.y * 32;
    const int tx = threadIdx.x & 31, ty = threadIdx.x >> 5;   // 32 x 8
#pragma unroll
    for (int i = 0; i < 32; i += 8)
        tile[ty + i][tx] = in[(size_t)(r0 + ty + i) * C + c0 + tx];
    __syncthreads();
#pragma unroll
    for (int i = 0; i < 32; i += 8)
        out[(size_t)(c0 + ty + i) * R + r0 + tx] = (bf16)tile[tx][ty + i];
}

// ---------------------------------------------------------------------------
// MFMA GEMM: C[M x N] = A[M x K] * Bt[N x K]^T   (Bt row-major, k contiguous,
// already bf16). A is fp32 (converted during staging) or bf16.
// Block: 256 thr = 4 waves; tile 64(M) x 64(N), BK=32; each wave 2x2 16x16.
// Verified layouts (learn_hip m89/m91): A-frag A[m=lane&15][k=quad*8+j],
// B-frag B[k=quad*8+j][n=lane&15], D[row=quad*4+r][col=lane&15].
// ---------------------------------------------------------------------------
template <typename AT, typename OT>
__global__ __launch_bounds__(256) void gemm_k(const AT* __restrict__ A,
                                              const bf16* __restrict__ Bt,
                                              OT* __restrict__ C,
                                              int M, int K, int N) {
    __shared__ alignas(16) bf16 As[64][40];   // pad 32->40 (80B rows: 16B-mult)
    __shared__ alignas(16) bf16 Bs[64][40];
    const int m0 = blockIdx.y * 64, n0 = blockIdx.x * 64;
    const int tid  = threadIdx.x;
    const int w    = tid >> 6, L = tid & 63, quad = L >> 4, lid = L & 15;
    const int wm   = (w & 1) * 32, wn = (w >> 1) * 32;
    const int ar   = tid >> 2, ac = (tid & 3) * 8;   // staging: 64 rows x 32 cols

    floatx4 acc00 = {0.f, 0.f, 0.f, 0.f}, acc01 = {0.f, 0.f, 0.f, 0.f};
    floatx4 acc10 = {0.f, 0.f, 0.f, 0.f}, acc11 = {0.f, 0.f, 0.f, 0.f};

    for (int k0 = 0; k0 < K; k0 += 32) {
        __syncthreads();
        if constexpr (sizeof(AT) == 4) {        // fp32 A: load + convert
            const float* ap = (const float*)A + (size_t)(m0 + ar) * K + k0 + ac;
            float4 f0 = *(const float4*)ap;
            float4 f1 = *(const float4*)(ap + 4);
            bf16x8 av;
            av[0] = (bf16)f0.x; av[1] = (bf16)f0.y; av[2] = (bf16)f0.z; av[3] = (bf16)f0.w;
            av[4] = (bf16)f1.x; av[5] = (bf16)f1.y; av[6] = (bf16)f1.z; av[7] = (bf16)f1.w;
            *(bf16x8*)&As[ar][ac] = av;
        } else {                                // bf16 A: straight 16B copy
            *(bf16x8*)&As[ar][ac] =
                *(const bf16x8*)((const bf16*)A + (size_t)(m0 + ar) * K + k0 + ac);
        }
        *(bf16x8*)&Bs[ar][ac] = *(const bf16x8*)(Bt + (size_t)(n0 + ar) * K + k0 + ac);
        __syncthreads();

        bf16x8 a0 = *(const bf16x8*)&As[wm + lid][quad * 8];
        bf16x8 a1 = *(const bf16x8*)&As[wm + 16 + lid][quad * 8];
        bf16x8 b0 = *(const bf16x8*)&Bs[wn + lid][quad * 8];
        bf16x8 b1 = *(const bf16x8*)&Bs[wn + 16 + lid][quad * 8];
        acc00 = MFMA16(a0, b0, acc00);
        acc01 = MFMA16(a0, b1, acc01);
        acc10 = MFMA16(a1, b0, acc10);
        acc11 = MFMA16(a1, b1, acc11);
    }

#pragma unroll
    for (int r = 0; r < 4; ++r) {
        const size_t row0 = (size_t)(m0 + wm + quad * 4 + r);
        const size_t col0 = (size_t)(n0 + wn + lid);
        C[row0 * N + col0]             = (OT)acc00[r];
        C[row0 * N + col0 + 16]        = (OT)acc01[r];
        C[(row0 + 16) * N + col0]      = (OT)acc10[r];
        C[(row0 + 16) * N + col0 + 16] = (OT)acc11[r];
    }
}

// ---------------------------------------------------------------------------
// In-place RMSNorm (+scale) + RoPE on a (B,T,nheads,H) bf16 buffer.
// One wave per head-vector; lane L owns the rope pair (L, L+64).
// ---------------------------------------------------------------------------
__global__ __launch_bounds__(256) void rms_rope(bf16* __restrict__ buf,
                                                const float* __restrict__ scale,
                                                const int* __restrict__ start,
                                                int nheads) {
    const int gid = blockIdx.x * 4 + (threadIdx.x >> 6);
    const int L   = threadIdx.x & 63;
    const int t   = (gid / nheads) % Tc;
    const int b   = gid / (nheads * Tc);
    bf16* p = buf + (size_t)gid * Hc;

    float x1 = (float)p[L], x2 = (float)p[L + 64];
    float ss = x1 * x1 + x2 * x2;
#pragma unroll
    for (int off = 1; off < 64; off <<= 1) ss += __shfl_xor(ss, off);
    const float inv = 1.f / sqrtf(ss * (1.0f / 128.0f) + 1e-6f);
    const float y1 = scale[L] * x1 * inv;
    const float y2 = scale[L + 64] * x2 * inv;

    const int   pos = t - start[b];
    const float fr  = (float)L * (1.0f / 64.0f);          // 2j/128, j = L
    const float invf = 1.0f / powf(1.0e6f, fr);           // ROPE_THETA = 1e6
    const float ang = (float)pos * invf;
    float sn, cs;
    sincosf(ang, &sn, &cs);

    p[L]      = (bf16)(y1 * cs - y2 * sn);
    p[L + 64] = (bf16)(y2 * cs + y1 * sn);
}

// ---------------------------------------------------------------------------
// Causal GQA flash attention, fixed-shift softmax (|logit| <= 11.32 after
// RMSNorm, so p = exp(logit - 16), no running max, exact after final /sum).
// Block: (Tq=64 rows) x head x batch; 4 waves, 16 q-rows per wave; S-tiles
// of 32 keys, uniform across the block so V staging can use __syncthreads.
// ---------------------------------------------------------------------------
__global__ __launch_bounds__(256) void attn_kernel(const bf16* __restrict__ q,
                                                   const bf16* __restrict__ k,
                                                   const bf16* __restrict__ v,
                                                   bf16* __restrict__ outp,
                                                   const int* __restrict__ start) {
    __shared__ alignas(16) bf16 vT[128][40];     // V tile transposed [feat][key]
    __shared__ alignas(16) bf16 pS[4][16][40];   // per-wave P tile [qrow][key]

    const int tblk = blockIdx.x, n = blockIdx.y, b = blockIdx.z;
    const int kh   = n >> 2;                     // N/KH = 4
    const int tid  = threadIdx.x, w = tid >> 6, L = tid & 63;
    const int quad = L >> 4, lid = L & 15;
    const int t0   = tblk * 64 + w * 16;
    const int st   = start[b];

    // Q fragments (16 rows x 128 feats), resident in registers.
    const bf16* qrow = q + ((size_t)(b * Tc + t0 + lid) * NHc + n) * Hc;
    bf16x8 aqf[4];
#pragma unroll
    for (int c = 0; c < 4; ++c) aqf[c] = *(const bf16x8*)(qrow + c * 32 + quad * 8);

    floatx4 oacc[8] = {};                        // O accumulator (16 x 128)
    float lsum[4] = {0.f, 0.f, 0.f, 0.f};        // per-lane partial row sums

    const int sEnd = tblk * 64 + 64;             // block-uniform (causal bound)
    const int vkey = tid >> 3;                   // staging: key 0..31
    const int vch  = tid & 7;                    // staging: feature chunk

    for (int s0 = 0; s0 < sEnd; s0 += 32) {
        __syncthreads();                          // protect prior-iter vT reads
        // Stage V tile (32 keys x 128 feats) transposed into LDS.
#pragma unroll
        for (int i = 0; i < 2; ++i) {
            const int ch = vch + i * 8;           // 0..15
            bf16x8 vv = *(const bf16x8*)(v + ((size_t)(b * Tc + s0 + vkey) * KHc + kh) * Hc + ch * 8);
#pragma unroll
            for (int j = 0; j < 8; ++j) vT[ch * 8 + j][vkey] = vv[j];
        }
        __syncthreads();

        // ---- QK^T: 16 queries x 32 keys ----
        floatx4 sc0 = {0.f, 0.f, 0.f, 0.f}, sc1 = {0.f, 0.f, 0.f, 0.f};
        const bf16* krow0 = k + ((size_t)(b * Tc + s0 + lid) * KHc + kh) * Hc;
        const bf16* krow1 = k + ((size_t)(b * Tc + s0 + 16 + lid) * KHc + kh) * Hc;
#pragma unroll
        for (int c = 0; c < 4; ++c) {
            bf16x8 bk0 = *(const bf16x8*)(krow0 + c * 32 + quad * 8);
            bf16x8 bk1 = *(const bf16x8*)(krow1 + c * 32 + quad * 8);
            sc0 = MFMA16(aqf[c], bk0, sc0);
            sc1 = MFMA16(aqf[c], bk1, sc1);
        }

        // ---- mask + exp (fixed shift 16) + write P to LDS (C->A layout) ----
#pragma unroll
        for (int r = 0; r < 4; ++r) {
            const int tq  = t0 + quad * 4 + r;
            const int sk0 = s0 + lid, sk1 = s0 + 16 + lid;
            const float p0 = (sk0 <= tq && sk0 >= st)
                               ? __expf(sc0[r] * 0.08838834764831845f - 16.f) : 0.f;
            const float p1 = (sk1 <= tq && sk1 >= st)
                               ? __expf(sc1[r] * 0.08838834764831845f - 16.f) : 0.f;
            lsum[r] += p0 + p1;
            pS[w][quad * 4 + r][lid]      = (bf16)p0;
            pS[w][quad * 4 + r][16 + lid] = (bf16)p1;
        }
        // Same-wave LDS RAW: force write->read ordering.
        asm volatile("s_waitcnt lgkmcnt(0)" ::: "memory");

        // ---- PV: P (16x32) * V (32x128) ----
        bf16x8 pa = *(const bf16x8*)&pS[w][lid][quad * 8];
#pragma unroll
        for (int cg = 0; cg < 8; ++cg) {
            bf16x8 bv = *(const bf16x8*)&vT[cg * 16 + lid][quad * 8];
            oacc[cg] = MFMA16(pa, bv, oacc[cg]);
        }
    }

    // Row sums: reduce across the 16 lanes of each quad.
#pragma unroll
    for (int r = 0; r < 4; ++r) {
        lsum[r] += __shfl_xor(lsum[r], 1);
        lsum[r] += __shfl_xor(lsum[r], 2);
        lsum[r] += __shfl_xor(lsum[r], 4);
        lsum[r] += __shfl_xor(lsum[r], 8);
    }

#pragma unroll
    for (int cg = 0; cg < 8; ++cg) {
#pragma unroll
        for (int r = 0; r < 4; ++r) {
            const int t = t0 + quad * 4 + r;
            outp[((size_t)(b * Tc + t) * NHc + n) * Hc + cg * 16 + lid] =
                (bf16)(oacc[cg][r] / lsum[r]);
        }
    }
}

// ---------------------------------------------------------------------------
// Orchestration. Workspace layout (88 MB + 4):
//   [0,32M)  wT   : wqT, later reused for woT
//   [32,40M) wkT   [40,48M) wvT
//   [48,64M) qb (B,T,N,H) bf16   [64,68M) kb   [68,72M) vb
//   [72,88M) ab (attention out, bf16)
//   [88M]    start[B]
// ---------------------------------------------------------------------------
extern "C" void kernel_launch(void* const* d_in, const int* in_sizes, int n_in,
                              void* d_out, int out_size, void* d_ws, size_t ws_size,
                              hipStream_t stream) {
    const float* x       = (const float*)d_in[0];
    const float* wq      = (const float*)d_in[1];
    const float* wk      = (const float*)d_in[2];
    const float* wv      = (const float*)d_in[3];
    const float* wo      = (const float*)d_in[4];
    const float* q_scale = (const float*)d_in[5];
    const float* k_scale = (const float*)d_in[6];
    const int*   seg     = (const int*)d_in[9];
    float*       out     = (float*)d_out;

    char* ws = (char*)d_ws;
    bf16* wT  = (bf16*)(ws);
    bf16* wkT = (bf16*)(ws + (32ull << 20));
    bf16* wvT = (bf16*)(ws + (40ull << 20));
    bf16* qb  = (bf16*)(ws + (48ull << 20));
    bf16* kb  = (bf16*)(ws + (64ull << 20));
    bf16* vb  = (bf16*)(ws + (68ull << 20));
    bf16* ab  = (bf16*)(ws + (72ull << 20));
    int*  stb = (int*) (ws + (88ull << 20));

    seg_scan<<<1, 64, 0, stream>>>(seg, stb);

    transpose_cvt<<<dim3(128, 128), 256, 0, stream>>>(wq, wT,  Dc, NHc * Hc);
    transpose_cvt<<<dim3(32,  128), 256, 0, stream>>>(wk, wkT, Dc, KHc * Hc);
    transpose_cvt<<<dim3(32,  128), 256, 0, stream>>>(wv, wvT, Dc, KHc * Hc);

    gemm_k<float, bf16><<<dim3(64, 32), 256, 0, stream>>>(x, wT,  qb, Bc * Tc, Dc, NHc * Hc);
    gemm_k<float, bf16><<<dim3(16, 32), 256, 0, stream>>>(x, wkT, kb, Bc * Tc, Dc, KHc * Hc);
    gemm_k<float, bf16><<<dim3(16, 32), 256, 0, stream>>>(x, wvT, vb, Bc * Tc, Dc, KHc * Hc);

    rms_rope<<<(Bc * Tc * NHc) / 4, 256, 0, stream>>>(qb, q_scale, stb, NHc);
    rms_rope<<<(Bc * Tc * KHc) / 4, 256, 0, stream>>>(kb, k_scale, stb, KHc);

    attn_kernel<<<dim3(Tc / 64, NHc, Bc), 256, 0, stream>>>(qb, kb, vb, ab, stb);

    transpose_cvt<<<dim3(128, 128), 256, 0, stream>>>(wo, wT, NHc * Hc, Dc);
    gemm_k<bf16, float><<<dim3(64, 32), 256, 0, stream>>>(ab, wT, out, Bc * Tc, NHc * Hc, Dc);
}

// Round 2
// 627.443 us; speedup vs baseline: 1.4222x; 1.4222x over previous
//
#include <hip/hip_runtime.h>

// ---------------------------------------------------------------------------
// Fixed problem shape: B=2, T=1024, D=4096, N=32 q-heads, KH=8 kv-heads, H=128.
// ---------------------------------------------------------------------------
constexpr int Bc  = 2;
constexpr int Tc  = 1024;
constexpr int Dc  = 4096;
constexpr int NHc = 32;
constexpr int KHc = 8;
constexpr int Hc  = 128;

typedef __bf16 bf16;
typedef bf16  bf16x8  __attribute__((ext_vector_type(8)));
typedef float floatx4 __attribute__((ext_vector_type(4)));

#define MFMA16(a, b, c) __builtin_amdgcn_mfma_f32_16x16x32_bf16((a), (b), (c), 0, 0, 0)

// Async global->LDS DMA, 16 bytes/lane. LDS dest is wave-uniform base +
// lane*16 (m104/m108 caveat) — the lane->LDS map is fixed; we pick each
// lane's GLOBAL source to implement the swizzled tile layout for free.
__device__ __forceinline__ void gload_lds16(const bf16* g, bf16* l) {
    __builtin_amdgcn_global_load_lds(
        (const __attribute__((address_space(1))) void*)g,
        (__attribute__((address_space(3))) void*)l, 16, 0, 0);
}

// ---------------------------------------------------------------------------
// start[b] = index of first nonzero segment id.
// ---------------------------------------------------------------------------
__global__ void seg_scan(const int* __restrict__ seg, int* __restrict__ start) {
    int b = threadIdx.x;
    if (b >= Bc) return;
    int f = 0;
    for (int t = 0; t < Tc; ++t) {
        if (seg[b * Tc + t] != 0) { f = t; break; }
    }
    start[b] = f;
}

// ---------------------------------------------------------------------------
// fp32 -> bf16 convert (x pre-pass), 8 elems/thread vectorized.
// ---------------------------------------------------------------------------
__global__ __launch_bounds__(256) void cvt_f32_bf16(const float* __restrict__ in,
                                                    bf16* __restrict__ out) {
    const size_t i = ((size_t)blockIdx.x * 256 + threadIdx.x) * 8;
    float4 f0 = *(const float4*)(in + i);
    float4 f1 = *(const float4*)(in + i + 4);
    bf16x8 v;
    v[0] = (bf16)f0.x; v[1] = (bf16)f0.y; v[2] = (bf16)f0.z; v[3] = (bf16)f0.w;
    v[4] = (bf16)f1.x; v[5] = (bf16)f1.y; v[6] = (bf16)f1.z; v[7] = (bf16)f1.w;
    *(bf16x8*)(out + i) = v;
}

// ---------------------------------------------------------------------------
// Transpose + fp32->bf16 convert:  out[C x R] = in[R x C]^T. 32x32 LDS tile.
// ---------------------------------------------------------------------------
__global__ __launch_bounds__(256) void transpose_cvt(const float* __restrict__ in,
                                                     bf16* __restrict__ out,
                                                     int R, int C) {
    __shared__ float tile[32][33];
    const int c0 = blockIdx.x * 32, r0 = blockIdx.y * 32;
    const int tx = threadIdx.x & 31, ty = threadIdx.x >> 5;   // 32 x 8
#pragma unroll
    for (int i = 0; i < 32; i += 8)
        tile[ty + i][tx] = in[(size_t)(r0 + ty + i) * C + c0 + tx];
    __syncthreads();
#pragma unroll
    for (int i = 0; i < 32; i += 8)
        out[(size_t)(c0 + ty + i) * R + r0 + tx] = (bf16)tile[tx][ty + i];
}

// ---------------------------------------------------------------------------
// m97-class MFMA GEMM: C[M x N] = A[M x K] * Bt[N x K]^T, all bf16 in.
// 256 thr = 4 waves in 2x2; tile 128x128, BK=32; 4x4 16x16x32 frags/wave.
// global_load_lds width=16 staging; XOR chunk swizzle (pos = quad^((row>>1)&3))
// makes fragment ds_read_b128 2-way bank-aliased (free, m136).
// Layouts (m89/m91): A-frag A[m=lid][k=quad*8+j], B-frag B[k=quad*8+j][n=lid],
// D[row=quad*4+r][col=lid].
// ---------------------------------------------------------------------------
template <typename OT>
__global__ __launch_bounds__(256) void gemm128(const bf16* __restrict__ A,
                                               const bf16* __restrict__ Bt,
                                               OT* __restrict__ C,
                                               int M, int K, int N) {
    __shared__ alignas(16) bf16 As[128 * 32];   // 8 KB, row = 32 elems = 64 B
    __shared__ alignas(16) bf16 Bs[128 * 32];
    const int m0 = blockIdx.y * 128, n0 = blockIdx.x * 128;
    const int tid = threadIdx.x;
    const int w = tid >> 6, L = tid & 63, quad = L >> 4, lid = L & 15;
    const int wm = (w & 1) * 64, wn = (w >> 1) * 64;

    // Staging: wave w fills rows [w*32, w*32+32) of As and Bs (2 instrs each).
    // Lane L -> row w*32 + (L>>2) (+16 for 2nd instr), stored chunk pos L&3.
    // Swizzle: stored pos p of row r holds logical chunk p ^ ((r>>1)&3);
    // for both instrs this reduces to c = (L&3) ^ ((L>>3)&3).
    const int srow = w * 32 + (L >> 2);
    const int chk  = (L & 3) ^ ((L >> 3) & 3);
    const bf16* gA = A  + (size_t)(m0 + srow) * K + chk * 8;
    const bf16* gB = Bt + (size_t)(n0 + srow) * K + chk * 8;
    bf16* lA0 = &As[(w * 32) * 32];
    bf16* lA1 = &As[(w * 32 + 16) * 32];
    bf16* lB0 = &Bs[(w * 32) * 32];
    bf16* lB1 = &Bs[(w * 32 + 16) * 32];

    // Loop-invariant swizzled fragment pointers.
    const bf16* ap[4]; const bf16* bp[4];
#pragma unroll
    for (int i = 0; i < 4; ++i) {
        const int ra = wm + i * 16 + lid;
        ap[i] = &As[ra * 32 + (quad ^ ((ra >> 1) & 3)) * 8];
        const int rb = wn + i * 16 + lid;
        bp[i] = &Bs[rb * 32 + (quad ^ ((rb >> 1) & 3)) * 8];
    }

    floatx4 acc[4][4] = {};

    for (int k0 = 0; k0 < K; k0 += 32) {
        __syncthreads();                       // prior-iter reads done
        gload_lds16(gA + k0,                 lA0);
        gload_lds16(gA + (size_t)16 * K + k0, lA1);
        gload_lds16(gB + k0,                 lB0);
        gload_lds16(gB + (size_t)16 * K + k0, lB1);
        __syncthreads();                       // DMA drained (vmcnt(0))

        bf16x8 af[4], bfr[4];
#pragma unroll
        for (int i = 0; i < 4; ++i) af[i]  = *(const bf16x8*)ap[i];
#pragma unroll
        for (int j = 0; j < 4; ++j) bfr[j] = *(const bf16x8*)bp[j];
#pragma unroll
        for (int i = 0; i < 4; ++i)
#pragma unroll
            for (int j = 0; j < 4; ++j)
                acc[i][j] = MFMA16(af[i], bfr[j], acc[i][j]);
    }

#pragma unroll
    for (int i = 0; i < 4; ++i) {
#pragma unroll
        for (int r = 0; r < 4; ++r) {
            const size_t row = (size_t)(m0 + wm + i * 16 + quad * 4 + r);
#pragma unroll
            for (int j = 0; j < 4; ++j)
                C[row * N + (n0 + wn + j * 16 + lid)] = (OT)acc[i][j][r];
        }
    }
}

// ---------------------------------------------------------------------------
// In-place RMSNorm (+scale) + RoPE on head-vectors living in a strided buffer:
// vector (b,t,h) at buf + (b*T+t)*rowstride + h*128. One wave per vector.
// ---------------------------------------------------------------------------
__global__ __launch_bounds__(256) void rms_rope(bf16* __restrict__ buf,
                                                const float* __restrict__ scale,
                                                const int* __restrict__ start,
                                                int nheads, int rowstride) {
    const int gid = blockIdx.x * 4 + (threadIdx.x >> 6);
    const int L   = threadIdx.x & 63;
    const int h   = gid % nheads;
    const int t   = (gid / nheads) % Tc;
    const int b   = gid / (nheads * Tc);
    bf16* p = buf + (size_t)(b * Tc + t) * rowstride + h * Hc;

    float x1 = (float)p[L], x2 = (float)p[L + 64];
    float ss = x1 * x1 + x2 * x2;
#pragma unroll
    for (int off = 1; off < 64; off <<= 1) ss += __shfl_xor(ss, off);
    const float inv = 1.f / sqrtf(ss * (1.0f / 128.0f) + 1e-6f);
    const float y1 = scale[L] * x1 * inv;
    const float y2 = scale[L + 64] * x2 * inv;

    const int   pos = t - start[b];
    const float fr  = (float)L * (1.0f / 64.0f);
    const float invf = 1.0f / powf(1.0e6f, fr);          // ROPE_THETA = 1e6
    const float ang = (float)pos * invf;
    float sn, cs;
    sincosf(ang, &sn, &cs);

    p[L]      = (bf16)(y1 * cs - y2 * sn);
    p[L + 64] = (bf16)(y2 * cs + y1 * sn);
}

// ---------------------------------------------------------------------------
// Causal GQA flash attention, fixed-shift softmax (post-RMSNorm |logit| <=
// sqrt(128)*sqrt(128)/sqrt(128) ~ 11.3, so p = exp(logit-16): no running max,
// exact after final /sum). Strided Q and KV (fused-qkv buffer).
// ---------------------------------------------------------------------------
__global__ __launch_bounds__(256) void attn_kernel(const bf16* __restrict__ q,
                                                   const bf16* __restrict__ k,
                                                   const bf16* __restrict__ v,
                                                   bf16* __restrict__ outp,
                                                   const int* __restrict__ start,
                                                   int qstride, int kvstride) {
    __shared__ alignas(16) bf16 vT[128][40];     // V tile transposed [feat][key]
    __shared__ alignas(16) bf16 pS[4][16][40];   // per-wave P tile [qrow][key]

    const int tblk = blockIdx.x, n = blockIdx.y, b = blockIdx.z;
    const int kh   = n >> 2;                     // N/KH = 4
    const int tid  = threadIdx.x, w = tid >> 6, L = tid & 63;
    const int quad = L >> 4, lid = L & 15;
    const int t0   = tblk * 64 + w * 16;
    const int st   = start[b];

    const bf16* qrow = q + (size_t)(b * Tc + t0 + lid) * qstride + n * Hc;
    bf16x8 aqf[4];
#pragma unroll
    for (int c = 0; c < 4; ++c) aqf[c] = *(const bf16x8*)(qrow + c * 32 + quad * 8);

    floatx4 oacc[8] = {};
    float lsum[4] = {0.f, 0.f, 0.f, 0.f};

    const int sEnd = tblk * 64 + 64;
    const int vkey = tid >> 3;
    const int vch  = tid & 7;

    for (int s0 = 0; s0 < sEnd; s0 += 32) {
        __syncthreads();
#pragma unroll
        for (int i = 0; i < 2; ++i) {
            const int ch = vch + i * 8;
            bf16x8 vv = *(const bf16x8*)(v + (size_t)(b * Tc + s0 + vkey) * kvstride + kh * Hc + ch * 8);
#pragma unroll
            for (int j = 0; j < 8; ++j) vT[ch * 8 + j][vkey] = vv[j];
        }
        __syncthreads();

        floatx4 sc0 = {0.f, 0.f, 0.f, 0.f}, sc1 = {0.f, 0.f, 0.f, 0.f};
        const bf16* krow0 = k + (size_t)(b * Tc + s0 + lid) * kvstride + kh * Hc;
        const bf16* krow1 = k + (size_t)(b * Tc + s0 + 16 + lid) * kvstride + kh * Hc;
#pragma unroll
        for (int c = 0; c < 4; ++c) {
            bf16x8 bk0 = *(const bf16x8*)(krow0 + c * 32 + quad * 8);
            bf16x8 bk1 = *(const bf16x8*)(krow1 + c * 32 + quad * 8);
            sc0 = MFMA16(aqf[c], bk0, sc0);
            sc1 = MFMA16(aqf[c], bk1, sc1);
        }

#pragma unroll
        for (int r = 0; r < 4; ++r) {
            const int tq  = t0 + quad * 4 + r;
            const int sk0 = s0 + lid, sk1 = s0 + 16 + lid;
            const float p0 = (sk0 <= tq && sk0 >= st)
                               ? __expf(sc0[r] * 0.08838834764831845f - 16.f) : 0.f;
            const float p1 = (sk1 <= tq && sk1 >= st)
                               ? __expf(sc1[r] * 0.08838834764831845f - 16.f) : 0.f;
            lsum[r] += p0 + p1;
            pS[w][quad * 4 + r][lid]      = (bf16)p0;
            pS[w][quad * 4 + r][16 + lid] = (bf16)p1;
        }
        asm volatile("s_waitcnt lgkmcnt(0)" ::: "memory");

        bf16x8 pa = *(const bf16x8*)&pS[w][lid][quad * 8];
#pragma unroll
        for (int cg = 0; cg < 8; ++cg) {
            bf16x8 bv = *(const bf16x8*)&vT[cg * 16 + lid][quad * 8];
            oacc[cg] = MFMA16(pa, bv, oacc[cg]);
        }
    }

#pragma unroll
    for (int r = 0; r < 4; ++r) {
        lsum[r] += __shfl_xor(lsum[r], 1);
        lsum[r] += __shfl_xor(lsum[r], 2);
        lsum[r] += __shfl_xor(lsum[r], 4);
        lsum[r] += __shfl_xor(lsum[r], 8);
    }

#pragma unroll
    for (int cg = 0; cg < 8; ++cg) {
#pragma unroll
        for (int r = 0; r < 4; ++r) {
            const int t = t0 + quad * 4 + r;
            outp[((size_t)(b * Tc + t) * NHc + n) * Hc + cg * 16 + lid] =
                (bf16)(oacc[cg][r] / lsum[r]);
        }
    }
}

// ---------------------------------------------------------------------------
// Workspace layout (88 MB + 8 B):
//   [0,48M)  wcomb : [wqT(4096 rows) ; wkT(1024) ; wvT(1024)] x 4096 bf16;
//            rows 0-4095 reused for woT before the out-proj.
//   [48,72M) qkvb  : [2048][6144] bf16 (q cols 0-4095, k 4096-5119, v 5120-6143)
//   [72,88M) xb (bf16 x) -> overlaid by ab (attention out) after QKV GEMM
//   [88M)    start[B]
// ---------------------------------------------------------------------------
extern "C" void kernel_launch(void* const* d_in, const int* in_sizes, int n_in,
                              void* d_out, int out_size, void* d_ws, size_t ws_size,
                              hipStream_t stream) {
    const float* x       = (const float*)d_in[0];
    const float* wq      = (const float*)d_in[1];
    const float* wk      = (const float*)d_in[2];
    const float* wv      = (const float*)d_in[3];
    const float* wo      = (const float*)d_in[4];
    const float* q_scale = (const float*)d_in[5];
    const float* k_scale = (const float*)d_in[6];
    const int*   seg     = (const int*)d_in[9];
    float*       out     = (float*)d_out;

    char* ws = (char*)d_ws;
    bf16* wcomb = (bf16*)(ws);
    bf16* qkvb  = (bf16*)(ws + (48ull << 20));
    bf16* xb    = (bf16*)(ws + (72ull << 20));
    bf16* ab    = xb;                               // overlay (xb dead by then)
    int*  stb   = (int*) (ws + (88ull << 20));

    seg_scan<<<1, 64, 0, stream>>>(seg, stb);

    cvt_f32_bf16<<<(Bc * Tc * Dc) / (256 * 8), 256, 0, stream>>>(x, xb);

    transpose_cvt<<<dim3(128, 128), 256, 0, stream>>>(wq, wcomb, Dc, NHc * Hc);
    transpose_cvt<<<dim3(32, 128), 256, 0, stream>>>(wk, wcomb + (size_t)4096 * Dc, Dc, KHc * Hc);
    transpose_cvt<<<dim3(32, 128), 256, 0, stream>>>(wv, wcomb + (size_t)5120 * Dc, Dc, KHc * Hc);

    // Fused QKV projection: [2048 x 4096] * [6144 x 4096]^T -> [2048 x 6144]
    gemm128<bf16><<<dim3(48, 16), 256, 0, stream>>>(xb, wcomb, qkvb,
                                                    Bc * Tc, Dc, 6144);

    rms_rope<<<(Bc * Tc * NHc) / 4, 256, 0, stream>>>(qkvb, q_scale, stb, NHc, 6144);
    rms_rope<<<(Bc * Tc * KHc) / 4, 256, 0, stream>>>(qkvb + 4096, k_scale, stb, KHc, 6144);

    attn_kernel<<<dim3(Tc / 64, NHc, Bc), 256, 0, stream>>>(
        qkvb, qkvb + 4096, qkvb + 5120, ab, stb, 6144, 6144);

    // Out projection: woT into wcomb rows 0-4095, then [2048x4096]*[4096x4096]^T
    transpose_cvt<<<dim3(128, 128), 256, 0, stream>>>(wo, wcomb, NHc * Hc, Dc);
    gemm128<float><<<dim3(32, 16), 256, 0, stream>>>(ab, wcomb, out,
                                                     Bc * Tc, NHc * Hc, Dc);
}

// Round 4
// 555.876 us; speedup vs baseline: 1.6053x; 1.1287x over previous
//
#include <hip/hip_runtime.h>

// ---------------------------------------------------------------------------
// Fixed problem shape: B=2, T=1024, D=4096, N=32 q-heads, KH=8 kv-heads, H=128.
// ---------------------------------------------------------------------------
constexpr int Bc  = 2;
constexpr int Tc  = 1024;
constexpr int Dc  = 4096;
constexpr int NHc = 32;
constexpr int KHc = 8;
constexpr int Hc  = 128;

typedef __bf16 bf16;
typedef bf16  bf16x4  __attribute__((ext_vector_type(4)));
typedef bf16  bf16x8  __attribute__((ext_vector_type(8)));
typedef float floatx4 __attribute__((ext_vector_type(4)));

#define MFMA16(a, b, c) __builtin_amdgcn_mfma_f32_16x16x32_bf16((a), (b), (c), 0, 0, 0)

// Async global->LDS DMA, 16 B/lane. LDS dest is wave-uniform base + lane*16
// (m104/m108) — lane->LDS map fixed; we pick each lane's GLOBAL source to
// implement swizzled tile layouts for free.
__device__ __forceinline__ void gload_lds16(const bf16* g, bf16* l) {
    __builtin_amdgcn_global_load_lds(
        (const __attribute__((address_space(1))) void*)g,
        (__attribute__((address_space(3))) void*)l, 16, 0, 0);
}

// ---------------------------------------------------------------------------
// start[b] = index of first nonzero segment id.
// ---------------------------------------------------------------------------
__global__ void seg_scan(const int* __restrict__ seg, int* __restrict__ start) {
    int b = threadIdx.x;
    if (b >= Bc) return;
    int f = 0;
    for (int t = 0; t < Tc; ++t) {
        if (seg[b * Tc + t] != 0) { f = t; break; }
    }
    start[b] = f;
}

// ---------------------------------------------------------------------------
// fp32 -> bf16 convert (x pre-pass), 8 elems/thread vectorized.
// ---------------------------------------------------------------------------
__global__ __launch_bounds__(256) void cvt_f32_bf16(const float* __restrict__ in,
                                                    bf16* __restrict__ out) {
    const size_t i = ((size_t)blockIdx.x * 256 + threadIdx.x) * 8;
    float4 f0 = *(const float4*)(in + i);
    float4 f1 = *(const float4*)(in + i + 4);
    bf16x8 v;
    v[0] = (bf16)f0.x; v[1] = (bf16)f0.y; v[2] = (bf16)f0.z; v[3] = (bf16)f0.w;
    v[4] = (bf16)f1.x; v[5] = (bf16)f1.y; v[6] = (bf16)f1.z; v[7] = (bf16)f1.w;
    *(bf16x8*)(out + i) = v;
}

// ---------------------------------------------------------------------------
// Transpose + fp32->bf16 convert: out[C x R] = in[R x C]^T. 64x64 tile,
// float4 loads (16 B/lane), bf16x4 stores (8 B/lane), +1 pad (2-way banks).
// ---------------------------------------------------------------------------
__global__ __launch_bounds__(256) void transpose_cvt(const float* __restrict__ in,
                                                     bf16* __restrict__ out,
                                                     int R, int C) {
    __shared__ float tile[64][65];
    const int c0 = blockIdx.x * 64, r0 = blockIdx.y * 64;
    const int tx = threadIdx.x & 15, ty = threadIdx.x >> 4;   // 16 x 16
#pragma unroll
    for (int i = 0; i < 4; ++i) {
        float4 f = *(const float4*)&in[(size_t)(r0 + ty * 4 + i) * C + c0 + tx * 4];
        tile[ty * 4 + i][tx * 4 + 0] = f.x;
        tile[ty * 4 + i][tx * 4 + 1] = f.y;
        tile[ty * 4 + i][tx * 4 + 2] = f.z;
        tile[ty * 4 + i][tx * 4 + 3] = f.w;
    }
    __syncthreads();
#pragma unroll
    for (int i = 0; i < 4; ++i) {
        const int cc = ty * 4 + i;
        bf16x4 v;
        v[0] = (bf16)tile[tx * 4 + 0][cc];
        v[1] = (bf16)tile[tx * 4 + 1][cc];
        v[2] = (bf16)tile[tx * 4 + 2][cc];
        v[3] = (bf16)tile[tx * 4 + 3][cc];
        *(bf16x4*)&out[(size_t)(c0 + cc) * R + r0 + tx * 4] = v;
    }
}

// ---------------------------------------------------------------------------
// V transpose: src = qkvb v-columns (strided rows), dst[b][kh][d][t] dense.
// Per block: one (b,kh), 32 t x 128 d tile.
// ---------------------------------------------------------------------------
__global__ __launch_bounds__(256) void v_transpose(const bf16* __restrict__ src,
                                                   bf16* __restrict__ dst,
                                                   int srcstride) {
    __shared__ bf16 tl[32][136];                 // 272B rows: 16B-aligned
    const int bk = blockIdx.y;                   // b*KHc + kh
    const int b = bk / KHc, kh = bk % KHc;
    const int t0 = blockIdx.x * 32;
    const int tid = threadIdx.x;
    {
        const int j = tid >> 3;                  // t row 0..31
        const int c = tid & 7;                   // d chunk of 16
        const bf16* p = src + (size_t)(b * Tc + t0 + j) * srcstride + kh * Hc + c * 16;
        *(bf16x8*)&tl[j][c * 16]     = *(const bf16x8*)p;
        *(bf16x8*)&tl[j][c * 16 + 8] = *(const bf16x8*)(p + 8);
    }
    __syncthreads();
    {
        const int d = tid >> 1;                  // 0..127
        const int toff = (tid & 1) * 16;
        bf16x8 v0, v1;
#pragma unroll
        for (int k = 0; k < 8; ++k) v0[k] = tl[toff + k][d];
#pragma unroll
        for (int k = 0; k < 8; ++k) v1[k] = tl[toff + 8 + k][d];
        bf16* o = dst + ((size_t)bk * Hc + d) * Tc + t0 + toff;
        *(bf16x8*)o       = v0;
        *(bf16x8*)(o + 8) = v1;
    }
}

// ---------------------------------------------------------------------------
// m97-class MFMA GEMM: C[M x N] = A[M x K] * Bt[N x K]^T, bf16 in.
// 128x128 tile, BK=32, global_load_lds width=16, XOR chunk swizzle.
// ---------------------------------------------------------------------------
template <typename OT>
__global__ __launch_bounds__(256) void gemm128(const bf16* __restrict__ A,
                                               const bf16* __restrict__ Bt,
                                               OT* __restrict__ C,
                                               int M, int K, int N) {
    __shared__ alignas(16) bf16 As[128 * 32];
    __shared__ alignas(16) bf16 Bs[128 * 32];
    const int m0 = blockIdx.y * 128, n0 = blockIdx.x * 128;
    const int tid = threadIdx.x;
    const int w = tid >> 6, L = tid & 63, quad = L >> 4, lid = L & 15;
    const int wm = (w & 1) * 64, wn = (w >> 1) * 64;

    const int srow = w * 32 + (L >> 2);
    const int chk  = (L & 3) ^ ((L >> 3) & 3);
    const bf16* gA = A  + (size_t)(m0 + srow) * K + chk * 8;
    const bf16* gB = Bt + (size_t)(n0 + srow) * K + chk * 8;
    bf16* lA0 = &As[(w * 32) * 32];
    bf16* lA1 = &As[(w * 32 + 16) * 32];
    bf16* lB0 = &Bs[(w * 32) * 32];
    bf16* lB1 = &Bs[(w * 32 + 16) * 32];

    const bf16* ap[4]; const bf16* bp[4];
#pragma unroll
    for (int i = 0; i < 4; ++i) {
        const int ra = wm + i * 16 + lid;
        ap[i] = &As[ra * 32 + (quad ^ ((ra >> 1) & 3)) * 8];
        const int rb = wn + i * 16 + lid;
        bp[i] = &Bs[rb * 32 + (quad ^ ((rb >> 1) & 3)) * 8];
    }

    floatx4 acc[4][4] = {};

    for (int k0 = 0; k0 < K; k0 += 32) {
        __syncthreads();
        gload_lds16(gA + k0,                  lA0);
        gload_lds16(gA + (size_t)16 * K + k0, lA1);
        gload_lds16(gB + k0,                  lB0);
        gload_lds16(gB + (size_t)16 * K + k0, lB1);
        __syncthreads();

        bf16x8 af[4], bfr[4];
#pragma unroll
        for (int i = 0; i < 4; ++i) af[i]  = *(const bf16x8*)ap[i];
#pragma unroll
        for (int j = 0; j < 4; ++j) bfr[j] = *(const bf16x8*)bp[j];
#pragma unroll
        for (int i = 0; i < 4; ++i)
#pragma unroll
            for (int j = 0; j < 4; ++j)
                acc[i][j] = MFMA16(af[i], bfr[j], acc[i][j]);
    }

#pragma unroll
    for (int i = 0; i < 4; ++i) {
#pragma unroll
        for (int r = 0; r < 4; ++r) {
            const size_t row = (size_t)(m0 + wm + i * 16 + quad * 4 + r);
#pragma unroll
            for (int j = 0; j < 4; ++j)
                C[row * N + (n0 + wn + j * 16 + lid)] = (OT)acc[i][j][r];
        }
    }
}

// ---------------------------------------------------------------------------
// In-place RMSNorm (+scale) + RoPE; one wave per head-vector (strided buffer).
// ---------------------------------------------------------------------------
__global__ __launch_bounds__(256) void rms_rope(bf16* __restrict__ buf,
                                                const float* __restrict__ scale,
                                                const int* __restrict__ start,
                                                int nheads, int rowstride) {
    const int gid = blockIdx.x * 4 + (threadIdx.x >> 6);
    const int L   = threadIdx.x & 63;
    const int h   = gid % nheads;
    const int t   = (gid / nheads) % Tc;
    const int b   = gid / (nheads * Tc);
    bf16* p = buf + (size_t)(b * Tc + t) * rowstride + h * Hc;

    float x1 = (float)p[L], x2 = (float)p[L + 64];
    float ss = x1 * x1 + x2 * x2;
#pragma unroll
    for (int off = 1; off < 64; off <<= 1) ss += __shfl_xor(ss, off);
    const float inv = 1.f / sqrtf(ss * (1.0f / 128.0f) + 1e-6f);
    const float y1 = scale[L] * x1 * inv;
    const float y2 = scale[L + 64] * x2 * inv;

    const int   pos = t - start[b];
    const float fr  = (float)L * (1.0f / 64.0f);
    const float invf = exp2f(-19.9315686f * fr);   // theta^-fr, theta=1e6
    const float ang = (float)pos * invf;
    float sn, cs;
    sincosf(ang, &sn, &cs);                        // accurate (large args)

    p[L]      = (bf16)(y1 * cs - y2 * sn);
    p[L + 64] = (bf16)(y2 * cs + y1 * sn);
}

// ---------------------------------------------------------------------------
// Causal GQA flash attention, fixed-shift softmax (post-RMSNorm |logit| <=
// 11.3 => p = exp(logit-16), exact after final /sum).
// K tile (32 s x 128 d, natural) and V^T tile (128 d x 32 s) staged via
// global_load_lds with XOR chunk swizzles; shared by all 4 waves.
// R3 BUG FIX: K staging source now includes + kh*Hc (was staging head 0's
// keys for every head).
// ---------------------------------------------------------------------------
__global__ __launch_bounds__(256) void attn_kernel(const bf16* __restrict__ q,
                                                   const bf16* __restrict__ k,
                                                   const bf16* __restrict__ vt,
                                                   bf16* __restrict__ outp,
                                                   const int* __restrict__ start,
                                                   int qstride, int kstride) {
    __shared__ alignas(16) bf16 Ks[32 * 128];    // row s (256 B), swizzled chunks
    __shared__ alignas(16) bf16 VT[128 * 32];    // row d (64 B), swizzled chunks
    __shared__ alignas(16) bf16 pS[4][16][40];   // per-wave P tile

    const int tblk = blockIdx.x, n = blockIdx.y, b = blockIdx.z;
    const int kh   = n >> 2;                     // N/KH = 4
    const int tid  = threadIdx.x, w = tid >> 6, L = tid & 63;
    const int quad = L >> 4, lid = L & 15;
    const int t0   = tblk * 64 + w * 16;
    const int st   = start[b];

    // Q fragments (16 rows x 128 feats) in registers.
    const bf16* qrow = q + (size_t)(b * Tc + t0 + lid) * qstride + n * Hc;
    bf16x8 aqf[4];
#pragma unroll
    for (int c = 0; c < 4; ++c) aqf[c] = *(const bf16x8*)(qrow + c * 32 + quad * 8);

    // K staging: instr i covers rows w*8+4i..+3; lane row = +L>>4, stored
    // chunk p=L&15 holds logical chunk p^(row&15).
    const int kr0 = w * 8 + (L >> 4);
    const int kr1 = kr0 + 4;
    const bf16* gK0 = k + (size_t)(b * Tc + kr0) * kstride + kh * Hc
                        + (((L & 15) ^ (kr0 & 15)) * 8);
    const bf16* gK1 = k + (size_t)(b * Tc + kr1) * kstride + kh * Hc
                        + (((L & 15) ^ (kr1 & 15)) * 8);
    bf16* lK0 = &Ks[(w * 8) * 128];
    bf16* lK1 = &Ks[(w * 8 + 4) * 128];

    // V^T staging: instr i covers d-rows (w*2+i)*16..+15; lane d = +L>>2,
    // stored pos p=L&3 holds logical chunk p^(d&3)^((d>>2)&3).
    const int vd0 = (w * 2) * 16 + (L >> 2);
    const int vd1 = vd0 + 16;
    const bf16* vbase = vt + (size_t)((b * KHc + kh) * Hc) * Tc;
    const bf16* gV0 = vbase + (size_t)vd0 * Tc + (((L & 3) ^ (vd0 & 3) ^ ((vd0 >> 2) & 3)) * 8);
    const bf16* gV1 = vbase + (size_t)vd1 * Tc + (((L & 3) ^ (vd1 & 3) ^ ((vd1 >> 2) & 3)) * 8);
    bf16* lV0 = &VT[(w * 2) * 512];
    bf16* lV1 = &VT[(w * 2 + 1) * 512];

    // Loop-invariant swizzled fragment pointers.
    const bf16* kf[4][2];
#pragma unroll
    for (int c = 0; c < 4; ++c) {
        kf[c][0] = &Ks[lid * 128        + (((c * 4 + quad) ^ lid) * 8)];
        kf[c][1] = &Ks[(16 + lid) * 128 + (((c * 4 + quad) ^ lid) * 8)];
    }
    const int vpos = (quad ^ (lid & 3) ^ ((lid >> 2) & 3)) * 8;
    const bf16* vf[8];
#pragma unroll
    for (int cg = 0; cg < 8; ++cg) vf[cg] = &VT[(cg * 16 + lid) * 32 + vpos];

    floatx4 oacc[8] = {};
    float lsum[4] = {0.f, 0.f, 0.f, 0.f};
    const int sEnd = tblk * 64 + 64;

    for (int s0 = 0; s0 < sEnd; s0 += 32) {
        __syncthreads();                         // prior-iter LDS reads done
        gload_lds16(gK0 + (size_t)s0 * kstride, lK0);
        gload_lds16(gK1 + (size_t)s0 * kstride, lK1);
        gload_lds16(gV0 + s0, lV0);
        gload_lds16(gV1 + s0, lV1);
        __syncthreads();                         // DMA drained

        // ---- QK^T: 16 q x 32 keys ----
        floatx4 sc0 = {0.f, 0.f, 0.f, 0.f}, sc1 = {0.f, 0.f, 0.f, 0.f};
#pragma unroll
        for (int c = 0; c < 4; ++c) {
            sc0 = MFMA16(aqf[c], *(const bf16x8*)kf[c][0], sc0);
            sc1 = MFMA16(aqf[c], *(const bf16x8*)kf[c][1], sc1);
        }

        // ---- mask + exp(shift 16) + P to LDS (C->A layout) ----
#pragma unroll
        for (int r = 0; r < 4; ++r) {
            const int tq  = t0 + quad * 4 + r;
            const int sk0 = s0 + lid, sk1 = s0 + 16 + lid;
            const float p0 = (sk0 <= tq && sk0 >= st)
                               ? __expf(sc0[r] * 0.08838834764831845f - 16.f) : 0.f;
            const float p1 = (sk1 <= tq && sk1 >= st)
                               ? __expf(sc1[r] * 0.08838834764831845f - 16.f) : 0.f;
            lsum[r] += p0 + p1;
            pS[w][quad * 4 + r][lid]      = (bf16)p0;
            pS[w][quad * 4 + r][16 + lid] = (bf16)p1;
        }
        asm volatile("s_waitcnt lgkmcnt(0)" ::: "memory");  // same-wave RAW

        // ---- PV: P (16x32) * V (32x128) ----
        bf16x8 pa = *(const bf16x8*)&pS[w][lid][quad * 8];
#pragma unroll
        for (int cg = 0; cg < 8; ++cg)
            oacc[cg] = MFMA16(pa, *(const bf16x8*)vf[cg], oacc[cg]);
    }

#pragma unroll
    for (int r = 0; r < 4; ++r) {
        lsum[r] += __shfl_xor(lsum[r], 1);
        lsum[r] += __shfl_xor(lsum[r], 2);
        lsum[r] += __shfl_xor(lsum[r], 4);
        lsum[r] += __shfl_xor(lsum[r], 8);
    }

#pragma unroll
    for (int cg = 0; cg < 8; ++cg) {
#pragma unroll
        for (int r = 0; r < 4; ++r) {
            const int t = t0 + quad * 4 + r;
            outp[((size_t)(b * Tc + t) * NHc + n) * Hc + cg * 16 + lid] =
                (bf16)(oacc[cg][r] / lsum[r]);
        }
    }
}

// ---------------------------------------------------------------------------
// Workspace layout (88 MB + 8 B):
//   [0,48M)  wcomb : [wqT;wkT;wvT] (6144 x 4096 bf16). After the QKV GEMM,
//            [0,32M) is overwritten by woT and [32,36M) by vtb (wkT dead).
//   [48,72M) qkvb  : [2048][6144] bf16 (q: 0-4095, k: 4096-5119, v: 5120-6143)
//   [72,88M) xb (bf16 x) -> overlaid by ab (attention out) after QKV GEMM
//   [88M)    start[B]
// ---------------------------------------------------------------------------
extern "C" void kernel_launch(void* const* d_in, const int* in_sizes, int n_in,
                              void* d_out, int out_size, void* d_ws, size_t ws_size,
                              hipStream_t stream) {
    const float* x       = (const float*)d_in[0];
    const float* wq      = (const float*)d_in[1];
    const float* wk      = (const float*)d_in[2];
    const float* wv      = (const float*)d_in[3];
    const float* wo      = (const float*)d_in[4];
    const float* q_scale = (const float*)d_in[5];
    const float* k_scale = (const float*)d_in[6];
    const int*   seg     = (const int*)d_in[9];
    float*       out     = (float*)d_out;

    char* ws = (char*)d_ws;
    bf16* wcomb = (bf16*)(ws);
    bf16* vtb   = (bf16*)(ws + (32ull << 20));      // overlay: dead wkT region
    bf16* qkvb  = (bf16*)(ws + (48ull << 20));
    bf16* xb    = (bf16*)(ws + (72ull << 20));
    bf16* ab    = xb;                               // overlay (xb dead by then)
    int*  stb   = (int*) (ws + (88ull << 20));

    seg_scan<<<1, 64, 0, stream>>>(seg, stb);

    cvt_f32_bf16<<<(Bc * Tc * Dc) / (256 * 8), 256, 0, stream>>>(x, xb);

    transpose_cvt<<<dim3(64, 64), 256, 0, stream>>>(wq, wcomb, Dc, NHc * Hc);
    transpose_cvt<<<dim3(16, 64), 256, 0, stream>>>(wk, wcomb + (size_t)4096 * Dc, Dc, KHc * Hc);
    transpose_cvt<<<dim3(16, 64), 256, 0, stream>>>(wv, wcomb + (size_t)5120 * Dc, Dc, KHc * Hc);

    // Fused QKV projection: [2048 x 4096] * [6144 x 4096]^T -> [2048 x 6144]
    gemm128<bf16><<<dim3(48, 16), 256, 0, stream>>>(xb, wcomb, qkvb,
                                                    Bc * Tc, Dc, 6144);

    rms_rope<<<(Bc * Tc * NHc) / 4, 256, 0, stream>>>(qkvb, q_scale, stb, NHc, 6144);
    rms_rope<<<(Bc * Tc * KHc) / 4, 256, 0, stream>>>(qkvb + 4096, k_scale, stb, KHc, 6144);

    v_transpose<<<dim3(Tc / 32, Bc * KHc), 256, 0, stream>>>(qkvb + 5120, vtb, 6144);

    // woT into wcomb[0,32M) (wqT dead after QKV GEMM).
    transpose_cvt<<<dim3(64, 64), 256, 0, stream>>>(wo, wcomb, NHc * Hc, Dc);

    attn_kernel<<<dim3(Tc / 64, NHc, Bc), 256, 0, stream>>>(
        qkvb, qkvb + 4096, vtb, ab, stb, 6144, 6144);

    // Out projection: [2048 x 4096] * [4096 x 4096]^T -> [2048 x 4096] fp32
    gemm128<float><<<dim3(32, 16), 256, 0, stream>>>(ab, wcomb, out,
                                                     Bc * Tc, NHc * Hc, Dc);
}